// Round 1
// baseline (1850.618 us; speedup 1.0000x reference)
//
#include <hip/hip_runtime.h>
#include <math.h>

#define BB 4096
#define HH 2048
#define NBK 4
#define HB 512

__device__ __forceinline__ float gelu_exact(float v) {
    // jax.nn.gelu(approximate=False) = 0.5*x*(1+erf(x/sqrt(2)))
    return 0.5f * v * (1.0f + erff(v * 0.70710678118654752f));
}

__device__ __forceinline__ float4 epi_apply(float4 v, int epi) {
    if (epi == 1) {
        v.x = gelu_exact(v.x); v.y = gelu_exact(v.y);
        v.z = gelu_exact(v.z); v.w = gelu_exact(v.w);
    }
    return v;
}

// C[M,N] = A[M,K] @ B[N,K]^T  (both row-major), optional epilogue.
// Batched via blockIdx.z with element offsets (0-stride for non-batched).
// Grid: (N/128, M/128, nbatch). Block: 256.
template<int EPI>
__global__ __launch_bounds__(256)
void sgemm_bt(const float* __restrict__ A, int lda, long batchA,
              const float* __restrict__ Bm, int ldb, long batchB,
              float* __restrict__ C, int ldc, long batchC,
              int K)
{
    constexpr int BM = 128, BN = 128, BK = 8;
    __shared__ float As[BK][BM];
    __shared__ float Bs[BK][BN];
    A  += (long)blockIdx.z * batchA;
    Bm += (long)blockIdx.z * batchB;
    C  += (long)blockIdx.z * batchC;

    const int tid  = threadIdx.x;
    const int tx   = tid & 15;        // 16 threads in N
    const int ty   = tid >> 4;        // 16 threads in M
    const int row0 = blockIdx.y * BM;
    const int col0 = blockIdx.x * BN;

    // staging: 128 rows x 8 k, one float4 per thread
    const int lrow = tid >> 1;        // 0..127
    const int lk   = (tid & 1) * 4;   // 0 or 4
    const float* Aload = A + (long)(row0 + lrow) * lda + lk;
    const float* Bload = Bm + (long)(col0 + lrow) * ldb + lk;

    float acc[8][8];
    #pragma unroll
    for (int i = 0; i < 8; ++i)
        #pragma unroll
        for (int j = 0; j < 8; ++j) acc[i][j] = 0.0f;

    for (int k0 = 0; k0 < K; k0 += BK) {
        const float4 av = *(const float4*)(Aload + k0);
        const float4 bv = *(const float4*)(Bload + k0);
        __syncthreads();
        As[lk + 0][lrow] = av.x; As[lk + 1][lrow] = av.y;
        As[lk + 2][lrow] = av.z; As[lk + 3][lrow] = av.w;
        Bs[lk + 0][lrow] = bv.x; Bs[lk + 1][lrow] = bv.y;
        Bs[lk + 2][lrow] = bv.z; Bs[lk + 3][lrow] = bv.w;
        __syncthreads();
        #pragma unroll
        for (int kk = 0; kk < BK; ++kk) {
            const float4 a0 = *(const float4*)&As[kk][ty * 4];
            const float4 a1 = *(const float4*)&As[kk][ty * 4 + 64];
            const float4 b0 = *(const float4*)&Bs[kk][tx * 4];
            const float4 b1 = *(const float4*)&Bs[kk][tx * 4 + 64];
            const float ar[8] = {a0.x, a0.y, a0.z, a0.w, a1.x, a1.y, a1.z, a1.w};
            const float br[8] = {b0.x, b0.y, b0.z, b0.w, b1.x, b1.y, b1.z, b1.w};
            #pragma unroll
            for (int i = 0; i < 8; ++i)
                #pragma unroll
                for (int j = 0; j < 8; ++j)
                    acc[i][j] = fmaf(ar[i], br[j], acc[i][j]);
        }
    }

    #pragma unroll
    for (int i = 0; i < 8; ++i) {
        const int r = row0 + ty * 4 + (i & 3) + (i >> 2) * 64;
        float4 v0, v1;
        v0.x = acc[i][0]; v0.y = acc[i][1]; v0.z = acc[i][2]; v0.w = acc[i][3];
        v1.x = acc[i][4]; v1.y = acc[i][5]; v1.z = acc[i][6]; v1.w = acc[i][7];
        v0 = epi_apply(v0, EPI);
        v1 = epi_apply(v1, EPI);
        *(float4*)&C[(long)r * ldc + col0 + tx * 4]      = v0;
        *(float4*)&C[(long)r * ldc + col0 + tx * 4 + 64] = v1;
    }
}

// xc = sum_k window[b,k,h]*conv_w[k,h] + conv_b[h]; also shifts conv_state.
__global__ void conv_kernel(const float* __restrict__ cs,   // [B,3,H]
                            const float* __restrict__ xr,   // [B,H]
                            const float* __restrict__ cw,   // [4,H]
                            const float* __restrict__ cb,   // [H]
                            float* __restrict__ xc,         // [B,H]
                            float* __restrict__ ncs)        // [B,3,H] (d_out section 2)
{
    const long idx = (long)blockIdx.x * blockDim.x + threadIdx.x;
    const long n4 = (long)BB * HH / 4;
    if (idx >= n4) return;
    const long b = idx / (HH / 4);
    const int  h = (int)(idx % (HH / 4)) * 4;

    const float4 c0 = *(const float4*)&cs[(b * 3 + 0) * HH + h];
    const float4 c1 = *(const float4*)&cs[(b * 3 + 1) * HH + h];
    const float4 c2 = *(const float4*)&cs[(b * 3 + 2) * HH + h];
    const float4 xv = *(const float4*)&xr[b * HH + h];
    const float4 w0 = *(const float4*)&cw[0 * HH + h];
    const float4 w1 = *(const float4*)&cw[1 * HH + h];
    const float4 w2 = *(const float4*)&cw[2 * HH + h];
    const float4 w3 = *(const float4*)&cw[3 * HH + h];
    const float4 bb = *(const float4*)&cb[h];

    float4 r;
    r.x = fmaf(c0.x, w0.x, fmaf(c1.x, w1.x, fmaf(c2.x, w2.x, fmaf(xv.x, w3.x, bb.x))));
    r.y = fmaf(c0.y, w0.y, fmaf(c1.y, w1.y, fmaf(c2.y, w2.y, fmaf(xv.y, w3.y, bb.y))));
    r.z = fmaf(c0.z, w0.z, fmaf(c1.z, w1.z, fmaf(c2.z, w2.z, fmaf(xv.z, w3.z, bb.z))));
    r.w = fmaf(c0.w, w0.w, fmaf(c1.w, w1.w, fmaf(c2.w, w2.w, fmaf(xv.w, w3.w, bb.w))));

    *(float4*)&xc[b * HH + h] = r;
    *(float4*)&ncs[(b * 3 + 0) * HH + h] = c1;
    *(float4*)&ncs[(b * 3 + 1) * HH + h] = c2;
    *(float4*)&ncs[(b * 3 + 2) * HH + h] = xv;
}

__device__ __forceinline__ float4 sigmoid4(float4 v) {
    v.x = 1.0f / (1.0f + expf(-v.x));
    v.y = 1.0f / (1.0f + expf(-v.y));
    v.z = 1.0f / (1.0f + expf(-v.z));
    v.w = 1.0f / (1.0f + expf(-v.w));
    return v;
}

// i=sig(yi), r=sig(yr), a_t=a^(8r), m=sqrt(1-a_t^2),
// nrs = rg*a_t + m*(i*xc), h = gate*nrs
__global__ void rglru_kernel(const float* __restrict__ yi,
                             const float* __restrict__ yr,
                             const float* __restrict__ xc,
                             const float* __restrict__ rg,
                             const float* __restrict__ av,   // [H]
                             const float* __restrict__ gate,
                             float* __restrict__ nrs,        // d_out section 3
                             float* __restrict__ hbuf)       // ws (in-place over gate)
{
    const long idx = (long)blockIdx.x * blockDim.x + threadIdx.x;
    const long n4 = (long)BB * HH / 4;
    if (idx >= n4) return;
    const long b = idx / (HH / 4);
    const int  h = (int)(idx % (HH / 4)) * 4;
    const long off = b * HH + h;

    const float4 i4 = sigmoid4(*(const float4*)&yi[off]);
    const float4 r4 = sigmoid4(*(const float4*)&yr[off]);
    const float4 x4 = *(const float4*)&xc[off];
    const float4 s4 = *(const float4*)&rg[off];
    const float4 a4 = *(const float4*)&av[h];
    const float4 g4 = *(const float4*)&gate[off];

    float4 at, o, hh;
    at.x = expf(8.0f * r4.x * logf(a4.x));
    at.y = expf(8.0f * r4.y * logf(a4.y));
    at.z = expf(8.0f * r4.z * logf(a4.z));
    at.w = expf(8.0f * r4.w * logf(a4.w));

    o.x = fmaf(s4.x, at.x, sqrtf(fmaxf(0.0f, 1.0f - at.x * at.x)) * (i4.x * x4.x));
    o.y = fmaf(s4.y, at.y, sqrtf(fmaxf(0.0f, 1.0f - at.y * at.y)) * (i4.y * x4.y));
    o.z = fmaf(s4.z, at.z, sqrtf(fmaxf(0.0f, 1.0f - at.z * at.z)) * (i4.z * x4.z));
    o.w = fmaf(s4.w, at.w, sqrtf(fmaxf(0.0f, 1.0f - at.w * at.w)) * (i4.w * x4.w));

    hh.x = g4.x * o.x; hh.y = g4.y * o.y; hh.z = g4.z * o.z; hh.w = g4.w * o.w;

    *(float4*)&nrs[off]  = o;
    *(float4*)&hbuf[off] = hh;
}

extern "C" void kernel_launch(void* const* d_in, const int* in_sizes, int n_in,
                              void* d_out, int out_size, void* d_ws, size_t ws_size,
                              hipStream_t stream) {
    const float* x    = (const float*)d_in[0];
    const float* cs   = (const float*)d_in[1];
    const float* rg   = (const float*)d_in[2];
    const float* Wg   = (const float*)d_in[3];
    const float* Wr   = (const float*)d_in[4];
    const float* Wo   = (const float*)d_in[5];
    const float* cw   = (const float*)d_in[6];
    const float* cb   = (const float*)d_in[7];
    const float* Wi   = (const float*)d_in[8];
    const float* Wrg  = (const float*)d_in[9];
    const float* av   = (const float*)d_in[10];

    const long BH = (long)BB * HH;
    float* out = (float*)d_out;            // [B,H]
    float* ncs = out + BH;                 // [B,3,H]
    float* nrs = out + 4 * BH;             // [B,H]

    float* ws   = (float*)d_ws;
    float* gate = ws;                      // [B,H]; later holds h = gate*nrs
    float* xr   = ws + BH;                 // [B,H]; reused as yi after conv
    float* xc   = ws + 2 * BH;             // [B,H]
    float* yi   = xr;
    float* yr   = out;                     // stage yr in d_out's out-slot; final GEMM overwrites

    const dim3 blk(256);
    const dim3 g1(HH / 128, BB / 128, 1);
    const dim3 g2(HB / 128, BB / 128, NBK);
    const int nElem4 = (int)(BH / 4);
    const dim3 ge((nElem4 + 255) / 256);

    // 1. gate = gelu(x @ Wg^T)
    sgemm_bt<1><<<g1, blk, 0, stream>>>(x, HH, 0, Wg, HH, 0, gate, HH, 0, HH);
    // 2. xr = x @ Wr^T
    sgemm_bt<0><<<g1, blk, 0, stream>>>(x, HH, 0, Wr, HH, 0, xr, HH, 0, HH);
    // 3. conv + state shift
    conv_kernel<<<ge, blk, 0, stream>>>(cs, xr, cw, cb, xc, ncs);
    // 4. yi = blockdiag(xc, Wi)   (overwrites xr)
    sgemm_bt<0><<<g2, blk, 0, stream>>>(xc, HH, HB, Wi, HB, (long)HB * HB, yi, HH, HB, HB);
    // 5. yr = blockdiag(xc, Wrg)  (staged in out-slot)
    sgemm_bt<0><<<g2, blk, 0, stream>>>(xc, HH, HB, Wrg, HB, (long)HB * HB, yr, HH, HB, HB);
    // 6. RG-LRU elementwise: nrs (final), h = gate*nrs (into gate buffer)
    rglru_kernel<<<ge, blk, 0, stream>>>(yi, yr, xc, rg, av, gate, nrs, gate);
    // 7. out = h @ Wo^T
    sgemm_bt<0><<<g1, blk, 0, stream>>>(gate, HH, 0, Wo, HH, 0, out, HH, 0, HH);
}

// Round 2
// 722.041 us; speedup vs baseline: 2.5630x; 2.5630x over previous
//
#include <hip/hip_runtime.h>
#include <math.h>

#define BB 4096
#define HH 2048
#define NBK 4
#define HB 512

typedef short bh8 __attribute__((ext_vector_type(8)));
typedef float f32x4 __attribute__((ext_vector_type(4)));

__device__ __forceinline__ float gelu_exact(float v) {
    return 0.5f * v * (1.0f + erff(v * 0.70710678118654752f));
}

// Convert 8 fp32 -> 8 bf16 hi (truncate) + 8 bf16 lo (residual, truncate),
// write 16B each into swizzled LDS slots.
__device__ __forceinline__ void cvt_store(char* hiB, char* loB, int row, int cb,
                                          float4 f0, float4 f1) {
    unsigned u0 = __float_as_uint(f0.x), u1 = __float_as_uint(f0.y),
             u2 = __float_as_uint(f0.z), u3 = __float_as_uint(f0.w),
             u4 = __float_as_uint(f1.x), u5 = __float_as_uint(f1.y),
             u6 = __float_as_uint(f1.z), u7 = __float_as_uint(f1.w);
    uint4 H;
    H.x = (u1 & 0xFFFF0000u) | (u0 >> 16);
    H.y = (u3 & 0xFFFF0000u) | (u2 >> 16);
    H.z = (u5 & 0xFFFF0000u) | (u4 >> 16);
    H.w = (u7 & 0xFFFF0000u) | (u6 >> 16);
    float l0 = f0.x - __uint_as_float(u0 & 0xFFFF0000u);
    float l1 = f0.y - __uint_as_float(u1 & 0xFFFF0000u);
    float l2 = f0.z - __uint_as_float(u2 & 0xFFFF0000u);
    float l3 = f0.w - __uint_as_float(u3 & 0xFFFF0000u);
    float l4 = f1.x - __uint_as_float(u4 & 0xFFFF0000u);
    float l5 = f1.y - __uint_as_float(u5 & 0xFFFF0000u);
    float l6 = f1.z - __uint_as_float(u6 & 0xFFFF0000u);
    float l7 = f1.w - __uint_as_float(u7 & 0xFFFF0000u);
    unsigned v0 = __float_as_uint(l0), v1 = __float_as_uint(l1),
             v2 = __float_as_uint(l2), v3 = __float_as_uint(l3),
             v4 = __float_as_uint(l4), v5 = __float_as_uint(l5),
             v6 = __float_as_uint(l6), v7 = __float_as_uint(l7);
    uint4 L;
    L.x = (v1 & 0xFFFF0000u) | (v0 >> 16);
    L.y = (v3 & 0xFFFF0000u) | (v2 >> 16);
    L.z = (v5 & 0xFFFF0000u) | (v4 >> 16);
    L.w = (v7 & 0xFFFF0000u) | (v6 >> 16);
    const int s = (cb ^ ((row >> 1) & 3)) * 16;   // XOR swizzle of 16B slot
    *(uint4*)(hiB + row * 64 + s) = H;
    *(uint4*)(loB + row * 64 + s) = L;
}

// C[M,N] = A[M,K] @ B[N,K]^T via split-bf16 MFMA: AhBh + AhBl + AlBh.
// 128x128 tile, BK=32, 4 waves (2x2 of 64x64), fp32->bf16 conversion fused
// into LDS staging. Batched via blockIdx.z element offsets.
template<int EPI>
__global__ __launch_bounds__(256, 2)
void bgemm_bt(const float* __restrict__ A, int lda, long batchA,
              const float* __restrict__ Bm, int ldb, long batchB,
              float* __restrict__ C, int ldc, long batchC, int K)
{
    constexpr int BK = 32;
    __shared__ uint4 ldsv[2048];                 // 32 KB
    char* lds = (char*)ldsv;
    char* Ah = lds;
    char* Al = lds + 8192;
    char* Bh = lds + 16384;
    char* Bl = lds + 24576;

    A  += (long)blockIdx.z * batchA;
    Bm += (long)blockIdx.z * batchB;
    C  += (long)blockIdx.z * batchC;

    const int tid  = threadIdx.x;
    const int row0 = blockIdx.y * 128;
    const int col0 = blockIdx.x * 128;

    // staging: thread -> (row sr / sr+64, 8-float col block scb)
    const int sr  = tid >> 2;
    const int scb = tid & 3;
    const float* Ald = A  + (long)(row0 + sr) * lda + scb * 8;
    const float* Bld = Bm + (long)(col0 + sr) * ldb + scb * 8;
    const long a64 = 64L * lda, b64 = 64L * ldb;

    // fragment coords
    const int lane = tid & 63;
    const int wr = (tid >> 7) & 1;               // wave row (0..1)
    const int wc = (tid >> 6) & 1;               // wave col (0..1)
    const int fm = lane & 15;
    const int kb = lane >> 4;
    const int slot = ((kb ^ ((fm >> 1) & 3)) & 3) * 16;
    const int aoff = (wr * 64 + fm) * 64 + slot; // + i*1024 per m-frag
    const int boff = (wc * 64 + fm) * 64 + slot; // + j*1024 per n-frag

    f32x4 acc[4][4] = {};

    float4 p0, p1, p2, p3, p4, p5, p6, p7;
    p0 = *(const float4*)(Ald);         p1 = *(const float4*)(Ald + 4);
    p2 = *(const float4*)(Ald + a64);   p3 = *(const float4*)(Ald + a64 + 4);
    p4 = *(const float4*)(Bld);         p5 = *(const float4*)(Bld + 4);
    p6 = *(const float4*)(Bld + b64);   p7 = *(const float4*)(Bld + b64 + 4);

    const int nkt = K / BK;
    for (int kt = 0; kt < nkt; ++kt) {
        __syncthreads();                          // prev compute done reading LDS
        cvt_store(Ah, Al, sr,      scb, p0, p1);
        cvt_store(Ah, Al, sr + 64, scb, p2, p3);
        cvt_store(Bh, Bl, sr,      scb, p4, p5);
        cvt_store(Bh, Bl, sr + 64, scb, p6, p7);
        __syncthreads();
        if (kt + 1 < nkt) {                       // prefetch next tile (hidden under MFMAs)
            const float* pa = Ald + (kt + 1) * BK;
            const float* pb = Bld + (kt + 1) * BK;
            p0 = *(const float4*)(pa);         p1 = *(const float4*)(pa + 4);
            p2 = *(const float4*)(pa + a64);   p3 = *(const float4*)(pa + a64 + 4);
            p4 = *(const float4*)(pb);         p5 = *(const float4*)(pb + 4);
            p6 = *(const float4*)(pb + b64);   p7 = *(const float4*)(pb + b64 + 4);
        }
        bh8 ahf[4], alf[4];
        #pragma unroll
        for (int i = 0; i < 4; ++i) {
            ahf[i] = *(const bh8*)(Ah + aoff + i * 1024);
            alf[i] = *(const bh8*)(Al + aoff + i * 1024);
        }
        #pragma unroll
        for (int j = 0; j < 4; ++j) {
            const bh8 bhf = *(const bh8*)(Bh + boff + j * 1024);
            const bh8 blf = *(const bh8*)(Bl + boff + j * 1024);
            #pragma unroll
            for (int i = 0; i < 4; ++i)
                acc[i][j] = __builtin_amdgcn_mfma_f32_16x16x32_bf16(ahf[i], bhf, acc[i][j], 0, 0, 0);
            #pragma unroll
            for (int i = 0; i < 4; ++i)
                acc[i][j] = __builtin_amdgcn_mfma_f32_16x16x32_bf16(ahf[i], blf, acc[i][j], 0, 0, 0);
            #pragma unroll
            for (int i = 0; i < 4; ++i)
                acc[i][j] = __builtin_amdgcn_mfma_f32_16x16x32_bf16(alf[i], bhf, acc[i][j], 0, 0, 0);
        }
    }

    // epilogue: D col = lane&15, row = (lane>>4)*4 + reg (verified m89 layout)
    const int erow = row0 + wr * 64 + (lane >> 4) * 4;
    const int ecol = col0 + wc * 64 + fm;
    #pragma unroll
    for (int i = 0; i < 4; ++i)
        #pragma unroll
        for (int j = 0; j < 4; ++j)
            #pragma unroll
            for (int r = 0; r < 4; ++r) {
                float v = acc[i][j][r];
                if (EPI == 1) v = gelu_exact(v);
                C[(long)(erow + i * 16 + r) * ldc + ecol + j * 16] = v;
            }
}

// xc = sum_k window[b,k,h]*conv_w[k,h] + conv_b[h]; also shifts conv_state.
__global__ void conv_kernel(const float* __restrict__ cs,   // [B,3,H]
                            const float* __restrict__ xr,   // [B,H]
                            const float* __restrict__ cw,   // [4,H]
                            const float* __restrict__ cb,   // [H]
                            float* __restrict__ xc,         // [B,H]
                            float* __restrict__ ncs)        // [B,3,H] (d_out section 2)
{
    const long idx = (long)blockIdx.x * blockDim.x + threadIdx.x;
    const long n4 = (long)BB * HH / 4;
    if (idx >= n4) return;
    const long b = idx / (HH / 4);
    const int  h = (int)(idx % (HH / 4)) * 4;

    const float4 c0 = *(const float4*)&cs[(b * 3 + 0) * HH + h];
    const float4 c1 = *(const float4*)&cs[(b * 3 + 1) * HH + h];
    const float4 c2 = *(const float4*)&cs[(b * 3 + 2) * HH + h];
    const float4 xv = *(const float4*)&xr[b * HH + h];
    const float4 w0 = *(const float4*)&cw[0 * HH + h];
    const float4 w1 = *(const float4*)&cw[1 * HH + h];
    const float4 w2 = *(const float4*)&cw[2 * HH + h];
    const float4 w3 = *(const float4*)&cw[3 * HH + h];
    const float4 bb = *(const float4*)&cb[h];

    float4 r;
    r.x = fmaf(c0.x, w0.x, fmaf(c1.x, w1.x, fmaf(c2.x, w2.x, fmaf(xv.x, w3.x, bb.x))));
    r.y = fmaf(c0.y, w0.y, fmaf(c1.y, w1.y, fmaf(c2.y, w2.y, fmaf(xv.y, w3.y, bb.y))));
    r.z = fmaf(c0.z, w0.z, fmaf(c1.z, w1.z, fmaf(c2.z, w2.z, fmaf(xv.z, w3.z, bb.z))));
    r.w = fmaf(c0.w, w0.w, fmaf(c1.w, w1.w, fmaf(c2.w, w2.w, fmaf(xv.w, w3.w, bb.w))));

    *(float4*)&xc[b * HH + h] = r;
    *(float4*)&ncs[(b * 3 + 0) * HH + h] = c1;
    *(float4*)&ncs[(b * 3 + 1) * HH + h] = c2;
    *(float4*)&ncs[(b * 3 + 2) * HH + h] = xv;
}

__device__ __forceinline__ float4 sigmoid4(float4 v) {
    v.x = 1.0f / (1.0f + expf(-v.x));
    v.y = 1.0f / (1.0f + expf(-v.y));
    v.z = 1.0f / (1.0f + expf(-v.z));
    v.w = 1.0f / (1.0f + expf(-v.w));
    return v;
}

// i=sig(yi), r=sig(yr), a_t=a^(8r), m=sqrt(1-a_t^2),
// nrs = rg*a_t + m*(i*xc), h = gate*nrs
__global__ void rglru_kernel(const float* __restrict__ yi,
                             const float* __restrict__ yr,
                             const float* __restrict__ xc,
                             const float* __restrict__ rg,
                             const float* __restrict__ av,   // [H]
                             const float* __restrict__ gate,
                             float* __restrict__ nrs,        // d_out section 3
                             float* __restrict__ hbuf)       // ws (in-place over gate)
{
    const long idx = (long)blockIdx.x * blockDim.x + threadIdx.x;
    const long n4 = (long)BB * HH / 4;
    if (idx >= n4) return;
    const long b = idx / (HH / 4);
    const int  h = (int)(idx % (HH / 4)) * 4;
    const long off = b * HH + h;

    const float4 i4 = sigmoid4(*(const float4*)&yi[off]);
    const float4 r4 = sigmoid4(*(const float4*)&yr[off]);
    const float4 x4 = *(const float4*)&xc[off];
    const float4 s4 = *(const float4*)&rg[off];
    const float4 a4 = *(const float4*)&av[h];
    const float4 g4 = *(const float4*)&gate[off];

    float4 at, o, hh;
    at.x = expf(8.0f * r4.x * logf(a4.x));
    at.y = expf(8.0f * r4.y * logf(a4.y));
    at.z = expf(8.0f * r4.z * logf(a4.z));
    at.w = expf(8.0f * r4.w * logf(a4.w));

    o.x = fmaf(s4.x, at.x, sqrtf(fmaxf(0.0f, 1.0f - at.x * at.x)) * (i4.x * x4.x));
    o.y = fmaf(s4.y, at.y, sqrtf(fmaxf(0.0f, 1.0f - at.y * at.y)) * (i4.y * x4.y));
    o.z = fmaf(s4.z, at.z, sqrtf(fmaxf(0.0f, 1.0f - at.z * at.z)) * (i4.z * x4.z));
    o.w = fmaf(s4.w, at.w, sqrtf(fmaxf(0.0f, 1.0f - at.w * at.w)) * (i4.w * x4.w));

    hh.x = g4.x * o.x; hh.y = g4.y * o.y; hh.z = g4.z * o.z; hh.w = g4.w * o.w;

    *(float4*)&nrs[off]  = o;
    *(float4*)&hbuf[off] = hh;
}

extern "C" void kernel_launch(void* const* d_in, const int* in_sizes, int n_in,
                              void* d_out, int out_size, void* d_ws, size_t ws_size,
                              hipStream_t stream) {
    const float* x    = (const float*)d_in[0];
    const float* cs   = (const float*)d_in[1];
    const float* rg   = (const float*)d_in[2];
    const float* Wg   = (const float*)d_in[3];
    const float* Wr   = (const float*)d_in[4];
    const float* Wo   = (const float*)d_in[5];
    const float* cw   = (const float*)d_in[6];
    const float* cb   = (const float*)d_in[7];
    const float* Wi   = (const float*)d_in[8];
    const float* Wrg  = (const float*)d_in[9];
    const float* av   = (const float*)d_in[10];

    const long BH = (long)BB * HH;
    float* out = (float*)d_out;            // [B,H]
    float* ncs = out + BH;                 // [B,3,H]
    float* nrs = out + 4 * BH;             // [B,H]

    float* ws   = (float*)d_ws;
    float* gate = ws;                      // [B,H]; later holds h = gate*nrs
    float* xr   = ws + BH;                 // [B,H]; reused as yi after conv
    float* xc   = ws + 2 * BH;             // [B,H]
    float* yi   = xr;
    float* yr   = out;                     // stage yr in out-slot; final GEMM overwrites

    const dim3 blk(256);
    const dim3 g1(HH / 128, BB / 128, 1);
    const dim3 g2(HB / 128, BB / 128, NBK);
    const int nElem4 = (int)(BH / 4);
    const dim3 ge((nElem4 + 255) / 256);

    // 1. gate = gelu(x @ Wg^T)
    bgemm_bt<1><<<g1, blk, 0, stream>>>(x, HH, 0, Wg, HH, 0, gate, HH, 0, HH);
    // 2. xr = x @ Wr^T
    bgemm_bt<0><<<g1, blk, 0, stream>>>(x, HH, 0, Wr, HH, 0, xr, HH, 0, HH);
    // 3. conv + state shift
    conv_kernel<<<ge, blk, 0, stream>>>(cs, xr, cw, cb, xc, ncs);
    // 4. yi = blockdiag(xc, Wi)   (overwrites xr)
    bgemm_bt<0><<<g2, blk, 0, stream>>>(xc, HH, HB, Wi, HB, (long)HB * HB, yi, HH, HB, HB);
    // 5. yr = blockdiag(xc, Wrg)  (staged in out-slot)
    bgemm_bt<0><<<g2, blk, 0, stream>>>(xc, HH, HB, Wrg, HB, (long)HB * HB, yr, HH, HB, HB);
    // 6. RG-LRU elementwise: nrs (final), h = gate*nrs (into gate buffer)
    rglru_kernel<<<ge, blk, 0, stream>>>(yi, yr, xc, rg, av, gate, nrs, gate);
    // 7. out = h @ Wo^T
    bgemm_bt<0><<<g1, blk, 0, stream>>>(gate, HH, 0, Wo, HH, 0, out, HH, 0, HH);
}